// Round 9
// baseline (173.162 us; speedup 1.0000x reference)
//
#include <hip/hip_runtime.h>
#include <hip/hip_bf16.h>
#include <stdint.h>
#include <stddef.h>

#define BATCH 256
#define OC 4096
#define IC 4096
#define VALUE_SCALE 0.1f

#define BN 64           // N-tile per WG (one 64-col slab shared by 4 m-waves)
#define BK 32           // K-step (elements)
#define KS 8            // split-K; ks = bid&7 pins K-slice to one XCD
#define KPER (IC / KS)  // 512
#define NT (KPER / BK)  // 16 K-steps
#define YSZ (BATCH * OC)

typedef float f32x4 __attribute__((ext_vector_type(4)));
typedef int   i32x4 __attribute__((ext_vector_type(4)));
typedef short bf16x8 __attribute__((ext_vector_type(8)));

__device__ __forceinline__ short f2bf(float f) {
    return (short)__bfloat16_as_ushort(__float2bfloat16(f));  // RNE
}

// ---------------- scatter: w[idx[i]] = val[i] * 0.1 (set; idempotent) ----------------
// R8 verdict: binned scatter regressed (total-gemm 105->122us); direct is the best
// measured variant (plain stores; nontemporal also regressed, R3).
__global__ void scatter_k(float* __restrict__ w, const int* __restrict__ idx,
                          const float* __restrict__ val, int n) {
    int i = (blockIdx.x * blockDim.x + threadIdx.x) * 4;
    if (i + 4 <= n) {
        i32x4 id = *(const i32x4*)(idx + i);
        f32x4 v  = *(const f32x4*)(val + i);
        w[id[0]] = v[0] * VALUE_SCALE;
        w[id[1]] = v[1] * VALUE_SCALE;
        w[id[2]] = v[2] * VALUE_SCALE;
        w[id[3]] = v[3] * VALUE_SCALE;
    } else {
        for (int j = i; j < n; ++j) w[idx[j]] = val[j] * VALUE_SCALE;
    }
}

// ======================= split-K bf16 GEMM — NO LDS, NO BARRIERS =======================
// R8 post-mortem: all LDS-staged variants (gload_lds, reg-staged) sat at 4-6x the
// L2 floor; the invariant cost was the 2-barrier-per-K-step lockstep, not staging
// style. This version loads MFMA fragments DIRECTLY global->VGPR->cvt->MFMA:
//  - B-frag pattern (16 rows x 128B contiguous) is fully 64B-line-coalesced; same A.
//  - zero inter-wave coupling: 8 independent waves/CU hide L2 latency.
//  - 1-step pipeline: loads for t+1 issue between cvt(t) and MFMA(t).
// Cost accepted: B read 4x-duplicated within WG (L2 has headroom).
// Wave = 64 rows x 64 cols = 4x4 frags of 16x16; block 256 = 4 m-waves;
// grid = (OC/BN)=64 n-tiles x KS=8 -> 512 WGs = 2 WG/CU. W read exactly once.
__global__ __launch_bounds__(256, 2) void gemm_k(const float* __restrict__ x,
                                                 const float* __restrict__ w,
                                                 float* __restrict__ part,
                                                 float* __restrict__ y) {
    const int tid  = threadIdx.x;
    const int lane = tid & 63;
    const int wv   = tid >> 6;      // 0..3 -> A rows wv*64..+64
    const int bid  = blockIdx.x;
    const int ks   = bid & 7;
    const int bn   = bid >> 3;
    const int k0   = ks * KPER;
    const int nc0  = bn * BN;

    const int r = lane & 15;        // frag row
    const int q = lane >> 4;        // frag k-chunk: k = q*8 .. q*8+8

    const float* xbase = x + (size_t)(wv * 64 + r) * IC + k0 + q * 8;
    const float* wbase = w + (size_t)(nc0 + r)     * IC + k0 + q * 8;

    f32x4 acc[4][4];
#pragma unroll
    for (int m = 0; m < 4; ++m)
#pragma unroll
        for (int n = 0; n < 4; ++n) acc[m][n] = (f32x4)0.0f;

    f32x4 ra[8], rb[8];     // in-flight fp32 frags (A: 4 frags x 32B, B: same)
    bf16x8 fa[4], fb[4];    // converted MFMA operands

    auto loadRaw = [&](int t) {
        const int ko = t * BK;
#pragma unroll
        for (int m = 0; m < 4; ++m) {            // A frag m: rows wv*64+m*16+r
            const float* s = xbase + (size_t)m * 16 * IC + ko;
            ra[2 * m]     = *(const f32x4*)s;
            ra[2 * m + 1] = *(const f32x4*)(s + 4);
        }
#pragma unroll
        for (int n = 0; n < 4; ++n) {            // B frag n: rows nc0+n*16+r
            const float* s = wbase + (size_t)n * 16 * IC + ko;
            rb[2 * n]     = *(const f32x4*)s;
            rb[2 * n + 1] = *(const f32x4*)(s + 4);
        }
    };

    auto cvtAll = [&]() {
#pragma unroll
        for (int m = 0; m < 4; ++m) {
#pragma unroll
            for (int j = 0; j < 4; ++j) {
                fa[m][j]     = f2bf(ra[2 * m][j]);
                fa[m][j + 4] = f2bf(ra[2 * m + 1][j]);
                fb[m][j]     = f2bf(rb[2 * m][j]);
                fb[m][j + 4] = f2bf(rb[2 * m + 1][j]);
            }
        }
    };

    loadRaw(0);
    for (int t = 0; t < NT; ++t) {
        cvtAll();                       // waits vmcnt for raw(t)
        if (t + 1 < NT) loadRaw(t + 1); // next-step loads fly under the MFMAs
#pragma unroll
        for (int n = 0; n < 4; ++n)
#pragma unroll
            for (int m = 0; m < 4; ++m)
                acc[m][n] = __builtin_amdgcn_mfma_f32_16x16x32_bf16(fa[m], fb[n], acc[m][n], 0, 0, 0);
    }

    // epilogue: C/D layout col=lane&15, row=(lane>>4)*4+reg  [proven R1..R8]
    if (part) {
        float* dst = part + (size_t)ks * YSZ;
#pragma unroll
        for (int m = 0; m < 4; ++m) {
            int r0 = wv * 64 + m * 16 + (lane >> 4) * 4;
#pragma unroll
            for (int n = 0; n < 4; ++n) {
                int c = nc0 + n * 16 + (lane & 15);
#pragma unroll
                for (int rr = 0; rr < 4; ++rr)
                    dst[(size_t)(r0 + rr) * OC + c] = acc[m][n][rr];
            }
        }
    } else {  // fallback when ws too small: atomic path (y pre-zeroed)
#pragma unroll
        for (int m = 0; m < 4; ++m) {
            int r0 = wv * 64 + m * 16 + (lane >> 4) * 4;
#pragma unroll
            for (int n = 0; n < 4; ++n) {
                int c = nc0 + n * 16 + (lane & 15);
#pragma unroll
                for (int rr = 0; rr < 4; ++rr)
                    atomicAdd(&y[(size_t)(r0 + rr) * OC + c], acc[m][n][rr]);
            }
        }
    }
}

// ---------------- reduce: y = sum of KS partial buffers (streaming, f32x4) ----------
__global__ void reduce_k(const float* __restrict__ part, float* __restrict__ y) {
    int i = (blockIdx.x * blockDim.x + threadIdx.x) * 4;
    f32x4 s = *(const f32x4*)(part + i);
#pragma unroll
    for (int p = 1; p < KS; ++p) s += *(const f32x4*)(part + (size_t)p * YSZ + i);
    *(f32x4*)(y + i) = s;
}

extern "C" void kernel_launch(void* const* d_in, const int* in_sizes, int n_in,
                              void* d_out, int out_size, void* d_ws, size_t ws_size,
                              hipStream_t stream) {
    const float* x  = (const float*)d_in[0];
    float*       w  = (float*)d_in[1];      // scattered in place (set = idempotent)
    const int*   fi = (const int*)d_in[2];
    const float* fv = (const float*)d_in[3];
    float*       y  = (float*)d_out;
    const int nflip = in_sizes[2];

    const bool use_ws = ws_size >= (size_t)KS * YSZ * sizeof(float);  // 32MB (taken, R4..R8)
    float* part = use_ws ? (float*)d_ws : nullptr;

    if (!use_ws) hipMemsetAsync(d_out, 0, (size_t)out_size * sizeof(float), stream);
    scatter_k<<<dim3((nflip + 1023) / 1024), dim3(256), 0, stream>>>(w, fi, fv, nflip);
    gemm_k<<<dim3((OC / BN) * KS), dim3(256), 0, stream>>>(x, w, part, y);
    if (use_ws)
        reduce_k<<<dim3(YSZ / (4 * 256)), dim3(256), 0, stream>>>(part, y);
}

// Round 10
// 151.835 us; speedup vs baseline: 1.1405x; 1.1405x over previous
//
#include <hip/hip_runtime.h>
#include <hip/hip_bf16.h>
#include <stdint.h>
#include <stddef.h>

#define BATCH 256
#define OC 4096
#define IC 4096
#define VALUE_SCALE 0.1f

#define BN 64           // N-tile per WG
#define BK 32           // K-step (elements)
#define KS 8            // split-K; ks = bid&7 pins K-slice to one XCD
#define KPER (IC / KS)  // 512
#define NT (KPER / BK)  // 16 K-steps
#define YSZ (BATCH * OC)

typedef float f32x4 __attribute__((ext_vector_type(4)));
typedef int   i32x4 __attribute__((ext_vector_type(4)));
typedef short bf16x8 __attribute__((ext_vector_type(8)));

__device__ __forceinline__ short f2bf(float f) {
    return (short)__bfloat16_as_ushort(__float2bfloat16(f));  // RNE
}

// lgkm-only barrier: never drains vmcnt -> in-flight global loads span it (T4)
__device__ __forceinline__ void barrier_nodrain() {
    asm volatile("s_waitcnt lgkmcnt(0)" ::: "memory");
    __builtin_amdgcn_sched_barrier(0);
    __builtin_amdgcn_s_barrier();
    __builtin_amdgcn_sched_barrier(0);
}

// ---------------- scatter: w[idx[i]] = val[i] * 0.1 (set; idempotent) ----------------
// Best measured variant (R6 direct ~34us; nontemporal +16us R3; binned +17us R8).
__global__ void scatter_k(float* __restrict__ w, const int* __restrict__ idx,
                          const float* __restrict__ val, int n) {
    int i = (blockIdx.x * blockDim.x + threadIdx.x) * 4;
    if (i + 4 <= n) {
        i32x4 id = *(const i32x4*)(idx + i);
        f32x4 v  = *(const f32x4*)(val + i);
        w[id[0]] = v[0] * VALUE_SCALE;
        w[id[1]] = v[1] * VALUE_SCALE;
        w[id[2]] = v[2] * VALUE_SCALE;
        w[id[3]] = v[3] * VALUE_SCALE;
    } else {
        for (int j = i; j < n; ++j) w[idx[j]] = val[j] * VALUE_SCALE;
    }
}

// ======================= split-K bf16 GEMM, 16 waves/CU =======================
// R9 post-mortem: removing barriers/LDS REGRESSED (41->68us) while FETCH/WRITE were
// unchanged -> limiter is W-load latency exposure at only 8 waves/CU, not sync or
// staging style. R10: keep R8's measured-best structure (reg-staged bf16 LDS,
// lgkm-only barriers, loads span barriers), double occupancy:
//   block 512 = 8 waves, wave = 32 M-rows x 64 N-cols (acc 2x4), WG = full M=256.
//   LDS 40KB/WG -> grid 512 = 2 WG x 8 waves = 16 waves/CU (4/SIMD).
// Staging per step: A thread: row tid>>1, half tid&1 (16 floats -> 2 bf16 chunks);
// B threads<256: row tid>>2, quarter tid&3 (8 floats -> 1 chunk). Chunk swizzle
// c' = c ^ ((row>>1)&3) on write and read (same involution both sides).
__global__ __launch_bounds__(512, 4) void gemm_k(const float* __restrict__ x,
                                                 const float* __restrict__ w,
                                                 float* __restrict__ part,
                                                 float* __restrict__ y) {
    const int tid  = threadIdx.x;
    const int lane = tid & 63;
    const int wv   = tid >> 6;      // 0..7 -> A rows wv*32..+32
    const int bid  = blockIdx.x;
    const int ks   = bid & 7;
    const int bn   = bid >> 3;
    const int k0   = ks * KPER;
    const int nc0  = bn * BN;

    __shared__ __align__(16) short At[2][BATCH * BK];  // 2 x 16KB bf16
    __shared__ __align__(16) short Bt[2][BN * BK];     // 2 x 4KB  -> 40KB total

    f32x4 acc[2][4];
#pragma unroll
    for (int m = 0; m < 2; ++m)
#pragma unroll
        for (int n = 0; n < 4; ++n) acc[m][n] = (f32x4)0.0f;

    const int arow = tid >> 1, ah = tid & 1;   // A: row, 16-float half
    const int brow = tid >> 2, bq = tid & 3;   // B: row, 8-float quarter (tid<256)

    f32x4 ra[4], rb[2];

    auto load_regs = [&](int t) {
        const float* s = x + (size_t)arow * IC + k0 + t * BK + ah * 16;
        ra[0] = *(const f32x4*)s;
        ra[1] = *(const f32x4*)(s + 4);
        ra[2] = *(const f32x4*)(s + 8);
        ra[3] = *(const f32x4*)(s + 12);
        if (tid < 256) {
            const float* sb = w + (size_t)(nc0 + brow) * IC + k0 + t * BK + bq * 8;
            rb[0] = *(const f32x4*)sb;
            rb[1] = *(const f32x4*)(sb + 4);
        }
    };

    auto write_lds = [&](int buf) {
        const int swa = (arow >> 1) & 3;
        bf16x8 v0, v1;
#pragma unroll
        for (int q = 0; q < 4; ++q) {
            v0[q] = f2bf(ra[0][q]); v0[q + 4] = f2bf(ra[1][q]);
            v1[q] = f2bf(ra[2][q]); v1[q + 4] = f2bf(ra[3][q]);
        }
        *(bf16x8*)&At[buf][arow * BK + ((2 * ah)     ^ swa) * 8] = v0;
        *(bf16x8*)&At[buf][arow * BK + ((2 * ah + 1) ^ swa) * 8] = v1;
        if (tid < 256) {
            bf16x8 vb;
#pragma unroll
            for (int q = 0; q < 4; ++q) { vb[q] = f2bf(rb[0][q]); vb[q + 4] = f2bf(rb[1][q]); }
            *(bf16x8*)&Bt[buf][brow * BK + (bq ^ ((brow >> 1) & 3)) * 8] = vb;
        }
    };

    auto compute = [&](int buf) {
        const int fr = lane & 15, cs = lane >> 4;   // frag row / k-chunk (proven map)
        bf16x8 a[2], b[4];
#pragma unroll
        for (int m = 0; m < 2; ++m) {
            int row = wv * 32 + m * 16 + fr;
            a[m] = *(const bf16x8*)&At[buf][row * BK + ((cs ^ ((row >> 1) & 3))) * 8];
        }
#pragma unroll
        for (int n = 0; n < 4; ++n) {
            int row = n * 16 + fr;
            b[n] = *(const bf16x8*)&Bt[buf][row * BK + ((cs ^ ((row >> 1) & 3))) * 8];
        }
#pragma unroll
        for (int n = 0; n < 4; ++n)
#pragma unroll
            for (int m = 0; m < 2; ++m)
                acc[m][n] = __builtin_amdgcn_mfma_f32_16x16x32_bf16(a[m], b[n], acc[m][n], 0, 0, 0);
    };

    // prologue
    load_regs(0);
    write_lds(0);
    barrier_nodrain();

    for (int t = 0; t < NT; ++t) {
        const int cur = t & 1;
        if (t + 1 < NT) load_regs(t + 1);   // loads stay in flight across barriers
        compute(cur);
        barrier_nodrain();                  // all reads of buf[cur] drained (lgkm0)
        if (t + 1 < NT) {
            write_lds(cur ^ 1);             // vmcnt wait lands at first ra/rb use
            barrier_nodrain();              // writes visible for next compute
        }
    }

    // epilogue: C/D layout col=lane&15, row=(lane>>4)*4+reg  [proven R1..R9]
    if (part) {
        float* dst = part + (size_t)ks * YSZ;
#pragma unroll
        for (int m = 0; m < 2; ++m) {
            int r0 = wv * 32 + m * 16 + (lane >> 4) * 4;
#pragma unroll
            for (int n = 0; n < 4; ++n) {
                int c = nc0 + n * 16 + (lane & 15);
#pragma unroll
                for (int rr = 0; rr < 4; ++rr)
                    dst[(size_t)(r0 + rr) * OC + c] = acc[m][n][rr];
            }
        }
    } else {  // fallback when ws too small: atomic path (y pre-zeroed)
#pragma unroll
        for (int m = 0; m < 2; ++m) {
            int r0 = wv * 32 + m * 16 + (lane >> 4) * 4;
#pragma unroll
            for (int n = 0; n < 4; ++n) {
                int c = nc0 + n * 16 + (lane & 15);
#pragma unroll
                for (int rr = 0; rr < 4; ++rr)
                    atomicAdd(&y[(size_t)(r0 + rr) * OC + c], acc[m][n][rr]);
            }
        }
    }
}

// ---------------- reduce: y = sum of KS partial buffers (streaming, f32x4) ----------
__global__ void reduce_k(const float* __restrict__ part, float* __restrict__ y) {
    int i = (blockIdx.x * blockDim.x + threadIdx.x) * 4;
    f32x4 s = *(const f32x4*)(part + i);
#pragma unroll
    for (int p = 1; p < KS; ++p) s += *(const f32x4*)(part + (size_t)p * YSZ + i);
    *(f32x4*)(y + i) = s;
}

extern "C" void kernel_launch(void* const* d_in, const int* in_sizes, int n_in,
                              void* d_out, int out_size, void* d_ws, size_t ws_size,
                              hipStream_t stream) {
    const float* x  = (const float*)d_in[0];
    float*       w  = (float*)d_in[1];      // scattered in place (set = idempotent)
    const int*   fi = (const int*)d_in[2];
    const float* fv = (const float*)d_in[3];
    float*       y  = (float*)d_out;
    const int nflip = in_sizes[2];

    const bool use_ws = ws_size >= (size_t)KS * YSZ * sizeof(float);  // 32MB (taken, R4..R9)
    float* part = use_ws ? (float*)d_ws : nullptr;

    if (!use_ws) hipMemsetAsync(d_out, 0, (size_t)out_size * sizeof(float), stream);
    scatter_k<<<dim3((nflip + 1023) / 1024), dim3(256), 0, stream>>>(w, fi, fv, nflip);
    gemm_k<<<dim3((OC / BN) * KS), dim3(512), 0, stream>>>(x, w, part, y);
    if (use_ws)
        reduce_k<<<dim3(YSZ / (4 * 256)), dim3(256), 0, stream>>>(part, y);
}

// Round 11
// 148.410 us; speedup vs baseline: 1.1668x; 1.0231x over previous
//
#include <hip/hip_runtime.h>
#include <hip/hip_bf16.h>
#include <stdint.h>
#include <stddef.h>

#define BATCH 256
#define OC 4096
#define IC 4096
#define VALUE_SCALE 0.1f

#define BN 64           // N-tile per WG
#define BK 32           // K-step (elements)
#define KS 8            // split-K; ks = bid&7 pins K-slice to one XCD
#define KPER (IC / KS)  // 512
#define NT (KPER / BK)  // 16 K-steps (even)
#define YSZ (BATCH * OC)

typedef float f32x4 __attribute__((ext_vector_type(4)));
typedef int   i32x4 __attribute__((ext_vector_type(4)));
typedef short bf16x8 __attribute__((ext_vector_type(8)));

__device__ __forceinline__ short f2bf(float f) {
    return (short)__bfloat16_as_ushort(__float2bfloat16(f));  // RNE
}

// lgkm-only barrier: never drains vmcnt -> in-flight global loads span it (T4)
__device__ __forceinline__ void barrier_nodrain() {
    asm volatile("s_waitcnt lgkmcnt(0)" ::: "memory");
    __builtin_amdgcn_sched_barrier(0);
    __builtin_amdgcn_s_barrier();
    __builtin_amdgcn_sched_barrier(0);
}

// ---------------- scatter: w[idx[i]] = val[i] * 0.1 (set; idempotent) ----------------
// Best measured variant (direct; nontemporal +16us R3; binned +17us R8).
__global__ void scatter_k(float* __restrict__ w, const int* __restrict__ idx,
                          const float* __restrict__ val, int n) {
    int i = (blockIdx.x * blockDim.x + threadIdx.x) * 4;
    if (i + 4 <= n) {
        i32x4 id = *(const i32x4*)(idx + i);
        f32x4 v  = *(const f32x4*)(val + i);
        w[id[0]] = v[0] * VALUE_SCALE;
        w[id[1]] = v[1] * VALUE_SCALE;
        w[id[2]] = v[2] * VALUE_SCALE;
        w[id[3]] = v[3] * VALUE_SCALE;
    } else {
        for (int j = i; j < n; ++j) w[idx[j]] = val[j] * VALUE_SCALE;
    }
}

// ======================= split-K bf16 GEMM, 2-deep pipeline =======================
// R10 post-mortem: occupancy 15->30% left gemm at ~44us; per-step cost pinned at
// ~6500cy across 5 structures while L2 floor ~1430cy -> exposed load latency in the
// 1-deep lockstep (loads got only ~600cy of cover vs ~900cy latency; vmcnt stall
// amplified by the barrier). R11: 2-deep pipeline — loads for step t+2 issue at top
// of step t; write_lds consumes loads issued ONE FULL STEP (~1300cy) earlier.
// Two named reg banks (static indexing, rule #20), loop unrolled x2.
// Block 512 = 8 waves, wave = 32Mx64N (acc 2x4); LDS 40KB/WG; grid 512 = 16 waves/CU.
// Chunk swizzle c' = c ^ ((row>>1)&3) on write and read (same involution).
__global__ __launch_bounds__(512, 4) void gemm_k(const float* __restrict__ x,
                                                 const float* __restrict__ w,
                                                 float* __restrict__ part,
                                                 float* __restrict__ y) {
    const int tid  = threadIdx.x;
    const int lane = tid & 63;
    const int wv   = tid >> 6;      // 0..7 -> A rows wv*32..+32
    const int bid  = blockIdx.x;
    const int ks   = bid & 7;
    const int bn   = bid >> 3;
    const int k0   = ks * KPER;
    const int nc0  = bn * BN;

    __shared__ __align__(16) short At[2][BATCH * BK];  // 2 x 16KB bf16
    __shared__ __align__(16) short Bt[2][BN * BK];     // 2 x 4KB  -> 40KB total

    f32x4 acc[2][4];
#pragma unroll
    for (int m = 0; m < 2; ++m)
#pragma unroll
        for (int n = 0; n < 4; ++n) acc[m][n] = (f32x4)0.0f;

    const int arow = tid >> 1, ah = tid & 1;   // A: row, 16-float half
    const int brow = tid >> 2, bq = tid & 3;   // B: row, 8-float quarter (tid<256)

    f32x4 ra0[4], rb0[2], ra1[4], rb1[2];      // two named in-flight banks

    auto load_regs = [&](int t, f32x4* ra, f32x4* rb) {
        const float* s = x + (size_t)arow * IC + k0 + t * BK + ah * 16;
        ra[0] = *(const f32x4*)s;
        ra[1] = *(const f32x4*)(s + 4);
        ra[2] = *(const f32x4*)(s + 8);
        ra[3] = *(const f32x4*)(s + 12);
        if (tid < 256) {
            const float* sb = w + (size_t)(nc0 + brow) * IC + k0 + t * BK + bq * 8;
            rb[0] = *(const f32x4*)sb;
            rb[1] = *(const f32x4*)(sb + 4);
        }
    };

    auto write_lds = [&](int buf, const f32x4* ra, const f32x4* rb) {
        const int swa = (arow >> 1) & 3;
        bf16x8 v0, v1;
#pragma unroll
        for (int q = 0; q < 4; ++q) {
            v0[q] = f2bf(ra[0][q]); v0[q + 4] = f2bf(ra[1][q]);
            v1[q] = f2bf(ra[2][q]); v1[q + 4] = f2bf(ra[3][q]);
        }
        *(bf16x8*)&At[buf][arow * BK + ((2 * ah)     ^ swa) * 8] = v0;
        *(bf16x8*)&At[buf][arow * BK + ((2 * ah + 1) ^ swa) * 8] = v1;
        if (tid < 256) {
            bf16x8 vb;
#pragma unroll
            for (int q = 0; q < 4; ++q) { vb[q] = f2bf(rb[0][q]); vb[q + 4] = f2bf(rb[1][q]); }
            *(bf16x8*)&Bt[buf][brow * BK + (bq ^ ((brow >> 1) & 3)) * 8] = vb;
        }
    };

    auto compute = [&](int buf) {
        const int fr = lane & 15, cs = lane >> 4;   // frag row / k-chunk (proven map)
        bf16x8 a[2], b[4];
#pragma unroll
        for (int m = 0; m < 2; ++m) {
            int row = wv * 32 + m * 16 + fr;
            a[m] = *(const bf16x8*)&At[buf][row * BK + ((cs ^ ((row >> 1) & 3))) * 8];
        }
#pragma unroll
        for (int n = 0; n < 4; ++n) {
            int row = n * 16 + fr;
            b[n] = *(const bf16x8*)&Bt[buf][row * BK + ((cs ^ ((row >> 1) & 3))) * 8];
        }
#pragma unroll
        for (int n = 0; n < 4; ++n)
#pragma unroll
            for (int m = 0; m < 2; ++m)
                acc[m][n] = __builtin_amdgcn_mfma_f32_16x16x32_bf16(a[m], b[n], acc[m][n], 0, 0, 0);
    };

    // prologue: tile0 staged; tile1 loads in flight
    load_regs(0, ra0, rb0);
    write_lds(0, ra0, rb0);       // waits bank0's own vmcnt
    load_regs(1, ra1, rb1);
    barrier_nodrain();

#pragma unroll 1
    for (int tt = 0; tt < NT / 2; ++tt) {
        const int t0 = 2 * tt, t1 = 2 * tt + 1;
        // ---- even step: compute buf0; issue load(t0+2)->bank0; stage buf1<-bank1(load t1)
        if (t0 + 2 < NT) load_regs(t0 + 2, ra0, rb0);   // bank0 free (consumed last tt)
        compute(0);
        barrier_nodrain();                               // reads of buf0 retired
        write_lds(1, ra1, rb1);                          // bank1 issued 1 full step ago
        barrier_nodrain();                               // buf1 visible
        // ---- odd step: compute buf1; issue load(t1+2)->bank1; stage buf0<-bank0
        if (t1 + 2 < NT) load_regs(t1 + 2, ra1, rb1);
        compute(1);
        barrier_nodrain();
        if (t0 + 2 < NT) {
            write_lds(0, ra0, rb0);                      // bank0 issued 1 full step ago
            barrier_nodrain();
        }
    }

    // epilogue: C/D layout col=lane&15, row=(lane>>4)*4+reg  [proven R1..R10]
    if (part) {
        float* dst = part + (size_t)ks * YSZ;
#pragma unroll
        for (int m = 0; m < 2; ++m) {
            int r0 = wv * 32 + m * 16 + (lane >> 4) * 4;
#pragma unroll
            for (int n = 0; n < 4; ++n) {
                int c = nc0 + n * 16 + (lane & 15);
#pragma unroll
                for (int rr = 0; rr < 4; ++rr)
                    dst[(size_t)(r0 + rr) * OC + c] = acc[m][n][rr];
            }
        }
    } else {  // fallback when ws too small: atomic path (y pre-zeroed)
#pragma unroll
        for (int m = 0; m < 2; ++m) {
            int r0 = wv * 32 + m * 16 + (lane >> 4) * 4;
#pragma unroll
            for (int n = 0; n < 4; ++n) {
                int c = nc0 + n * 16 + (lane & 15);
#pragma unroll
                for (int rr = 0; rr < 4; ++rr)
                    atomicAdd(&y[(size_t)(r0 + rr) * OC + c], acc[m][n][rr]);
            }
        }
    }
}

// ---------------- reduce: y = sum of KS partial buffers (streaming, f32x4) ----------
__global__ void reduce_k(const float* __restrict__ part, float* __restrict__ y) {
    int i = (blockIdx.x * blockDim.x + threadIdx.x) * 4;
    f32x4 s = *(const f32x4*)(part + i);
#pragma unroll
    for (int p = 1; p < KS; ++p) s += *(const f32x4*)(part + (size_t)p * YSZ + i);
    *(f32x4*)(y + i) = s;
}

extern "C" void kernel_launch(void* const* d_in, const int* in_sizes, int n_in,
                              void* d_out, int out_size, void* d_ws, size_t ws_size,
                              hipStream_t stream) {
    const float* x  = (const float*)d_in[0];
    float*       w  = (float*)d_in[1];      // scattered in place (set = idempotent)
    const int*   fi = (const int*)d_in[2];
    const float* fv = (const float*)d_in[3];
    float*       y  = (float*)d_out;
    const int nflip = in_sizes[2];

    const bool use_ws = ws_size >= (size_t)KS * YSZ * sizeof(float);  // 32MB (taken, R4..R10)
    float* part = use_ws ? (float*)d_ws : nullptr;

    if (!use_ws) hipMemsetAsync(d_out, 0, (size_t)out_size * sizeof(float), stream);
    scatter_k<<<dim3((nflip + 1023) / 1024), dim3(256), 0, stream>>>(w, fi, fv, nflip);
    gemm_k<<<dim3((OC / BN) * KS), dim3(512), 0, stream>>>(x, w, part, y);
    if (use_ws)
        reduce_k<<<dim3(YSZ / (4 * 256)), dim3(256), 0, stream>>>(part, y);
}

// Round 13
// 139.895 us; speedup vs baseline: 1.2378x; 1.0609x over previous
//
#include <hip/hip_runtime.h>
#include <hip/hip_bf16.h>
#include <stdint.h>
#include <stddef.h>

#define BATCH 256
#define OC 4096
#define IC 4096
#define VALUE_SCALE 0.1f

#define BN 64             // N-tile per WG
#define BK 32             // K-step (elements)
#define KS 8              // split-K; ks = bid&7 pins K-slice to one XCD
#define KPER (IC / KS)    // 512
#define NT (KPER / BK)    // 16 K-steps (even)
#define YSZ (BATCH * OC)
#define TILE_SHORTS (BATCH * BK)  // 8192 shorts = 16KB per A' K-step tile
#define PART_BYTES ((size_t)KS * YSZ * sizeof(float))   // 32MB
#define AP_BYTES   ((size_t)(IC / BK) * TILE_SHORTS * sizeof(short))  // 2MB

typedef float f32x4 __attribute__((ext_vector_type(4)));
typedef int   i32x4 __attribute__((ext_vector_type(4)));
typedef short bf16x8 __attribute__((ext_vector_type(8)));

__device__ __forceinline__ short f2bf(float f) {
    return (short)__bfloat16_as_ushort(__float2bfloat16(f));  // RNE
}

// lgkm-only barrier: never drains vmcnt -> in-flight global loads span it (T4)
__device__ __forceinline__ void barrier_nodrain() {
    asm volatile("s_waitcnt lgkmcnt(0)" ::: "memory");
    __builtin_amdgcn_sched_barrier(0);
    __builtin_amdgcn_s_barrier();
    __builtin_amdgcn_sched_barrier(0);
}

// ---------------- scatter: w[idx[i]] = val[i] * 0.1 (set; idempotent) ----------------
// Best measured variant (direct; nontemporal +16us R3; binned +17us R8). FROZEN.
__global__ void scatter_k(float* __restrict__ w, const int* __restrict__ idx,
                          const float* __restrict__ val, int n) {
    int i = (blockIdx.x * blockDim.x + threadIdx.x) * 4;
    if (i + 4 <= n) {
        i32x4 id = *(const i32x4*)(idx + i);
        f32x4 v  = *(const f32x4*)(val + i);
        w[id[0]] = v[0] * VALUE_SCALE;
        w[id[1]] = v[1] * VALUE_SCALE;
        w[id[2]] = v[2] * VALUE_SCALE;
        w[id[3]] = v[3] * VALUE_SCALE;
    } else {
        for (int j = i; j < n; ++j) w[idx[j]] = val[j] * VALUE_SCALE;
    }
}

// ---------------- prep: repack x (fp32 row-major) -> A' (bf16, per-step tiles) --------
// A'[tg][r][chunk] : tile tg = k-step (32 k), row r, 8-elem chunk stored at position
// q ^ ((r>>1)&3)  — the exact swizzled order R8-R11's write_lds produced (0 bank
// conflicts measured). Gemm then stages A as a LINEAR identity copy (fully coalesced).
__global__ void prep_k(const float* __restrict__ x, short* __restrict__ ap) {
    const int i = blockIdx.x * 256 + threadIdx.x;   // 131072 threads x 8 floats
    const int r = i >> 9;                            // 0..255
    const int k = (i & 511) * 8;                     // 0..4088
    const int tg = k >> 5;
    const int q  = (k >> 3) & 3;
    const float* s = x + (size_t)r * IC + k;         // coalesced read
    f32x4 lo = *(const f32x4*)s;
    f32x4 hi = *(const f32x4*)(s + 4);
    bf16x8 v;
#pragma unroll
    for (int j = 0; j < 4; ++j) { v[j] = f2bf(lo[j]); v[j + 4] = f2bf(hi[j]); }
    *(bf16x8*)&ap[(size_t)tg * TILE_SHORTS + r * BK + ((q ^ ((r >> 1) & 3)) * 8)] = v;
}

// ======================= split-K bf16 GEMM, 2-deep pipeline, coalesced A ==============
// R11 post-mortem: per-step cost ~6200cy matched TRANSACTION count (strided 16KB row
// reads fragment each wave-load into 16-32 L1 transactions), not latency/occupancy.
// R12/13: A staged from pre-swizzled A' tiles = linear identity copy, 2 coalesced 16B
// loads/thread (tile halves at tid*8 and 4096+tid*8 -> 16B-stride LDS writes,
// conflict-free), zero A cvt. B unchanged from R11 (reg-staged fp32->bf16, small).
// compute() byte-identical to R11 (proven frag map + swizzle + epilogue).
struct Bank { bf16x8 a0, a1; f32x4 b0, b1; };

__global__ __launch_bounds__(512, 4) void gemm_k(const short* __restrict__ ap,
                                                 const float* __restrict__ w,
                                                 float* __restrict__ part) {
    const int tid  = threadIdx.x;
    const int lane = tid & 63;
    const int wv   = tid >> 6;      // 0..7 -> A rows wv*32..+32
    const int bid  = blockIdx.x;
    const int ks   = bid & 7;
    const int bn   = bid >> 3;
    const int nc0  = bn * BN;
    const int k0   = ks * KPER;

    __shared__ __align__(16) short At[2][TILE_SHORTS];  // 2 x 16KB
    __shared__ __align__(16) short Bt[2][BN * BK];      // 2 x 4KB  -> 40KB

    f32x4 acc[2][4];
#pragma unroll
    for (int m = 0; m < 2; ++m)
#pragma unroll
        for (int n = 0; n < 4; ++n) acc[m][n] = (f32x4)0.0f;

    const int brow = tid >> 2, bq = tid & 3;   // B: row, 8-float quarter (tid<256)

    Bank bk0, bk1;

    auto load_regs = [&](int t, Bank& b) {
        const short* s = ap + (size_t)(ks * NT + t) * TILE_SHORTS;
        b.a0 = *(const bf16x8*)(s + tid * 8);            // coalesced 16B/lane
        b.a1 = *(const bf16x8*)(s + 4096 + tid * 8);
        if (tid < 256) {
            const float* sb = w + (size_t)(nc0 + brow) * IC + k0 + t * BK + bq * 8;
            b.b0 = *(const f32x4*)sb;
            b.b1 = *(const f32x4*)(sb + 4);
        }
    };

    auto write_lds = [&](int buf, const Bank& b) {
        *(bf16x8*)&At[buf][tid * 8]        = b.a0;       // 16B-stride: conflict-free
        *(bf16x8*)&At[buf][4096 + tid * 8] = b.a1;
        if (tid < 256) {
            bf16x8 vb;
#pragma unroll
            for (int q = 0; q < 4; ++q) { vb[q] = f2bf(b.b0[q]); vb[q + 4] = f2bf(b.b1[q]); }
            *(bf16x8*)&Bt[buf][brow * BK + (bq ^ ((brow >> 1) & 3)) * 8] = vb;
        }
    };

    auto compute = [&](int buf) {
        const int fr = lane & 15, cs = lane >> 4;   // frag row / k-chunk (proven map)
        bf16x8 a[2], b[4];
#pragma unroll
        for (int m = 0; m < 2; ++m) {
            int row = wv * 32 + m * 16 + fr;
            a[m] = *(const bf16x8*)&At[buf][row * BK + ((cs ^ ((row >> 1) & 3))) * 8];
        }
#pragma unroll
        for (int n = 0; n < 4; ++n) {
            int row = n * 16 + fr;
            b[n] = *(const bf16x8*)&Bt[buf][row * BK + ((cs ^ ((row >> 1) & 3))) * 8];
        }
#pragma unroll
        for (int n = 0; n < 4; ++n)
#pragma unroll
            for (int m = 0; m < 2; ++m)
                acc[m][n] = __builtin_amdgcn_mfma_f32_16x16x32_bf16(a[m], b[n], acc[m][n], 0, 0, 0);
    };

    // prologue: tile0 staged; tile1 loads in flight
    load_regs(0, bk0);
    write_lds(0, bk0);            // waits bank0's own vmcnt
    load_regs(1, bk1);
    barrier_nodrain();

#pragma unroll 1
    for (int tt = 0; tt < NT / 2; ++tt) {
        const int t0 = 2 * tt, t1 = 2 * tt + 1;
        if (t0 + 2 < NT) load_regs(t0 + 2, bk0);   // bank0 free (consumed last tt)
        compute(0);
        barrier_nodrain();                          // reads of buf0 retired
        write_lds(1, bk1);                          // bank1 issued 1 full step ago
        barrier_nodrain();                          // buf1 visible
        if (t1 + 2 < NT) load_regs(t1 + 2, bk1);
        compute(1);
        barrier_nodrain();
        if (t0 + 2 < NT) {
            write_lds(0, bk0);                      // bank0 issued 1 full step ago
            barrier_nodrain();
        }
    }

    // epilogue: C/D layout col=lane&15, row=(lane>>4)*4+reg  [proven R1..R11]
    float* dst = part + (size_t)ks * YSZ;
#pragma unroll
    for (int m = 0; m < 2; ++m) {
        int r0 = wv * 32 + m * 16 + (lane >> 4) * 4;
#pragma unroll
        for (int n = 0; n < 4; ++n) {
            int c = nc0 + n * 16 + (lane & 15);
#pragma unroll
            for (int rr = 0; rr < 4; ++rr)
                dst[(size_t)(r0 + rr) * OC + c] = acc[m][n][rr];
        }
    }
}

// ---------------- reduce: y = sum of KS partial buffers (streaming, f32x4) ----------
__global__ void reduce_k(const float* __restrict__ part, float* __restrict__ y) {
    int i = (blockIdx.x * blockDim.x + threadIdx.x) * 4;
    f32x4 s = *(const f32x4*)(part + i);
#pragma unroll
    for (int p = 1; p < KS; ++p) s += *(const f32x4*)(part + (size_t)p * YSZ + i);
    *(f32x4*)(y + i) = s;
}

// ---------------- naive fallback (only if ws too small; never observed) -------------
__global__ void naive_k(const float* __restrict__ x, const float* __restrict__ w,
                        float* __restrict__ y) {
    const int o = blockIdx.x;          // 0..4095
    const int b = threadIdx.x;         // 0..255
    const float* xr = x + (size_t)b * IC;
    const float* wr = w + (size_t)o * IC;
    float s = 0.f;
#pragma unroll 4
    for (int k = 0; k < IC; ++k) s += xr[k] * wr[k];
    y[(size_t)b * OC + o] = s;
}

extern "C" void kernel_launch(void* const* d_in, const int* in_sizes, int n_in,
                              void* d_out, int out_size, void* d_ws, size_t ws_size,
                              hipStream_t stream) {
    const float* x  = (const float*)d_in[0];
    float*       w  = (float*)d_in[1];      // scattered in place (set = idempotent)
    const int*   fi = (const int*)d_in[2];
    const float* fv = (const float*)d_in[3];
    float*       y  = (float*)d_out;
    const int nflip = in_sizes[2];

    const bool use_ws = ws_size >= PART_BYTES + AP_BYTES;   // 34MB (ws is 268MB, R8-R11)

    if (use_ws) {
        float* part = (float*)d_ws;
        short* ap   = (short*)((char*)d_ws + PART_BYTES);
        prep_k<<<dim3(512), dim3(256), 0, stream>>>(x, ap);
        scatter_k<<<dim3((nflip + 1023) / 1024), dim3(256), 0, stream>>>(w, fi, fv, nflip);
        gemm_k<<<dim3((OC / BN) * KS), dim3(512), 0, stream>>>(ap, w, part);
        reduce_k<<<dim3(YSZ / (4 * 256)), dim3(256), 0, stream>>>(part, y);
    } else {
        scatter_k<<<dim3((nflip + 1023) / 1024), dim3(256), 0, stream>>>(w, fi, fv, nflip);
        naive_k<<<dim3(OC), dim3(BATCH), 0, stream>>>(x, w, y);
    }
}